// Round 11
// baseline (136.072 us; speedup 1.0000x reference)
//
#include <hip/hip_runtime.h>
#include <hip/hip_bf16.h>

#define DIMD 512
#define NEXP 8
#define HIDN 2048
#define NTOK 4096
#define NASG 8192

typedef short bf16x8 __attribute__((ext_vector_type(8)));
typedef float f32x4 __attribute__((ext_vector_type(4)));

__device__ inline unsigned short f2bf(float f) {
  __hip_bfloat16 h = __float2bfloat16(f);
  return __builtin_bit_cast(unsigned short, h);
}

__device__ inline void gl16(const void* g, void* l) {
  __builtin_amdgcn_global_load_lds(
      (const __attribute__((address_space(1))) unsigned int*)g,
      (__attribute__((address_space(3))) unsigned int*)l, 16, 0, 0);
}

// Counted-vmcnt barrier discipline (T4).
#define PIPE_WAIT8_BAR() do { \
  asm volatile("s_waitcnt vmcnt(8)" ::: "memory"); \
  __builtin_amdgcn_s_barrier(); \
  __builtin_amdgcn_sched_barrier(0); } while (0)
#define PIPE_WAIT4_BAR() do { \
  asm volatile("s_waitcnt vmcnt(4)" ::: "memory"); \
  __builtin_amdgcn_s_barrier(); \
  __builtin_amdgcn_sched_barrier(0); } while (0)
#define PIPE_WAIT0_BAR() do { \
  asm volatile("s_waitcnt vmcnt(0)" ::: "memory"); \
  __builtin_amdgcn_s_barrier(); \
  __builtin_amdgcn_sched_barrier(0); } while (0)
#define PIPE_POST_BAR() do { \
  asm volatile("" ::: "memory"); \
  __builtin_amdgcn_sched_barrier(0); \
  __builtin_amdgcn_s_barrier(); } while (0)
#define PIPE_MID_BAR() do { \
  __builtin_amdgcn_s_barrier(); \
  __builtin_amdgcn_sched_barrier(0); } while (0)

// ---------- both W transposes in one launch: [E][R][C] fp32 -> [E][C][R] bf16 ----------
__global__ __launch_bounds__(256) void transpose_both_kernel(
    const float* __restrict__ W1, const float* __restrict__ W2,
    unsigned short* __restrict__ w1t, unsigned short* __restrict__ w2t) {
  __shared__ float tile[64][65];
  int z = blockIdx.z;
  int e = z & 7;
  const float* src; unsigned short* dst; int R, C, r0, c0;
  if (z < 8) { src = W1; dst = w1t; R = DIMD; C = HIDN; c0 = blockIdx.x * 64; r0 = blockIdx.y * 64; }
  else       { src = W2; dst = w2t; R = HIDN; C = DIMD; r0 = blockIdx.x * 64; c0 = blockIdx.y * 64; }
  const float* s = src + (size_t)e * R * C;
  unsigned short* d = dst + (size_t)e * R * C;
  for (int i = threadIdx.x; i < 4096; i += 256) {
    int r = i >> 6, c = i & 63;
    tile[r][c] = s[(size_t)(r0 + r) * C + (c0 + c)];
  }
  __syncthreads();
  for (int i = threadIdx.x; i < 2048; i += 256) {
    int c = i >> 5;
    int r = (i & 31) * 2;
    unsigned lo = f2bf(tile[r][c]);
    unsigned hi = f2bf(tile[r + 1][c]);
    *reinterpret_cast<unsigned*>(d + (size_t)(c0 + c) * R + (r0 + r)) = lo | (hi << 16);
  }
}

// ---------- router: logits, softmax, top-2, renorm; emits x in bf16. NO atomics. ----------
__global__ __launch_bounds__(256) void router_kernel(const float* __restrict__ x,
                                                     const float* __restrict__ Wr,
                                                     const float* __restrict__ br,
                                                     int* __restrict__ tidx,
                                                     float* __restrict__ tw,
                                                     unsigned short* __restrict__ xb) {
  int lane = threadIdx.x & 63;
  int n = blockIdx.x * 4 + (threadIdx.x >> 6);
  const float* xr = x + (size_t)n * DIMD;
  unsigned short* xbr = xb + (size_t)n * DIMD;
  float acc[NEXP];
#pragma unroll
  for (int e = 0; e < NEXP; ++e) acc[e] = 0.f;
#pragma unroll
  for (int it = 0; it < 2; ++it) {
    int d0 = it * 256 + lane * 4;
    float4 xv = *reinterpret_cast<const float4*>(xr + d0);
    unsigned p0 = (unsigned)f2bf(xv.x) | ((unsigned)f2bf(xv.y) << 16);
    unsigned p1 = (unsigned)f2bf(xv.z) | ((unsigned)f2bf(xv.w) << 16);
    *reinterpret_cast<uint2*>(xbr + d0) = make_uint2(p0, p1);
    const float* wr = Wr + (size_t)d0 * NEXP;
#pragma unroll
    for (int j = 0; j < 4; ++j) {
      float xj = (&xv.x)[j];
#pragma unroll
      for (int e = 0; e < NEXP; ++e) acc[e] += xj * wr[j * NEXP + e];
    }
  }
#pragma unroll
  for (int e = 0; e < NEXP; ++e) {
    float v = acc[e];
#pragma unroll
    for (int off = 32; off > 0; off >>= 1) v += __shfl_xor(v, off, 64);
    acc[e] = v + br[e];
  }
  if (lane == 0) {
    float m = acc[0];
    for (int e = 1; e < NEXP; ++e) m = fmaxf(m, acc[e]);
    float p[NEXP], s = 0.f;
    for (int e = 0; e < NEXP; ++e) { p[e] = expf(acc[e] - m); s += p[e]; }
    float inv = 1.f / s;
    for (int e = 0; e < NEXP; ++e) p[e] *= inv;
    int i0 = 0; float p0 = p[0];
    for (int e = 1; e < NEXP; ++e) if (p[e] > p0) { p0 = p[e]; i0 = e; }
    int i1 = (i0 == 0) ? 1 : 0; float p1 = p[i1];
    for (int e = 0; e < NEXP; ++e) if (e != i0 && p[e] > p1) { p1 = p[e]; i1 = e; }
    // reference renormalizes by softmax over the top-2 *probabilities*
    float t = expf(p1 - p0);
    float w0 = 1.f / (1.f + t);
    tidx[2 * n] = i0; tidx[2 * n + 1] = i1;
    tw[2 * n] = w0; tw[2 * n + 1] = t * w0;
  }
}

// ---------- route_pack: counts + offsets + stable scatter + lb tail, single block ----------
__global__ __launch_bounds__(1024) void route_pack_kernel(const int* __restrict__ tidx,
                                                          int* __restrict__ off,
                                                          int* __restrict__ list,
                                                          float* __restrict__ out_tail) {
  int tid = threadIdx.x;
  int wv = tid >> 6, lane = tid & 63;

  int ids[8];
#pragma unroll
  for (int j = 0; j < 8; ++j) ids[j] = tidx[tid * 8 + j];

  int c[NEXP];
#pragma unroll
  for (int e = 0; e < NEXP; ++e) c[e] = 0;
#pragma unroll
  for (int j = 0; j < 8; ++j)
#pragma unroll
    for (int e = 0; e < NEXP; ++e) c[e] += (ids[j] == e) ? 1 : 0;

  int inc[NEXP];
#pragma unroll
  for (int e = 0; e < NEXP; ++e) {
    int v = c[e];
#pragma unroll
    for (int d = 1; d < 64; d <<= 1) {
      int t = __shfl_up(v, d, 64);
      if (lane >= d) v += t;
    }
    inc[e] = v;
  }

  __shared__ int wtot[NEXP][16];
  __shared__ int wbase[NEXP][16];
  __shared__ int ebase[NEXP];
  if (lane == 63) {
#pragma unroll
    for (int e = 0; e < NEXP; ++e) wtot[e][wv] = inc[e];
  }
  __syncthreads();
  if (tid == 0) {
    int o = 0;
    float lb = 0.f;
    for (int e = 0; e < NEXP; ++e) {
      int s = 0;
      for (int w = 0; w < 16; ++w) { wbase[e][w] = s; s += wtot[e][w]; }
      ebase[e] = o;
      off[e] = o;
      o += s;
      float l = (float)s / (float)NASG;
      out_tail[1 + e] = l;
      float dd = l - 0.125f;
      lb += dd * dd;
    }
    off[NEXP] = o;
    out_tail[0] = lb;
  }
  __syncthreads();

  int pos[NEXP];
#pragma unroll
  for (int e = 0; e < NEXP; ++e)
    pos[e] = ebase[e] + wbase[e][wv] + (inc[e] - c[e]);

#pragma unroll
  for (int j = 0; j < 8; ++j) {
    int e = ids[j];
    int p = 0;
#pragma unroll
    for (int k = 0; k < NEXP; ++k)
      if (e == k) { p = pos[k]; pos[k] = p + 1; }
    list[p] = tid * 8 + j;
  }
}

// ===================== GEMM1: 256x256x(BK=64) 8-wave 8-phase template =====================
// LDS: A bufs [0,64K) (buf d at d*32768, halves 16K), B bufs [64K,128K).
// Row layout per half: row r (0..127) x 8 chunks of 16B: byte = r*128 + ((c ^ (r&7))<<4).
// Staged by gl16 (wave-uniform dest, lane*16) from pre-swizzled per-lane sources.
// Wave (2M x 4N): wave_m=wv>>2, wave_n=wv&3. Frag f (0..7): half=f>>2,
// row_in_half = wave_m*64 + (f&3)*16 + lane16. Phases 0-1 read A-half0, 2-3 A-half1.
// B frags cached in regs at phase 0. Prefetch distance 2 K-tiles, region-safe issue:
// B(kt+2) after ph0 end-bar, A-half0 after ph1, A-half1 after ph3. vmcnt(8) steady.

#define G1_PHASE(F0) do { \
  const char* Ah_ = A + ((F0) >> 2) * 16384; \
  int r0_ = (wave_m * 64 + (((F0)) & 3) * 16 + lane16) * 128; \
  int r1_ = (wave_m * 64 + (((F0) + 1) & 3) * 16 + lane16) * 128; \
  bf16x8 a00 = *reinterpret_cast<const bf16x8*>(Ah_ + r0_ + sw0); \
  bf16x8 a01 = *reinterpret_cast<const bf16x8*>(Ah_ + r0_ + sw1); \
  bf16x8 a10 = *reinterpret_cast<const bf16x8*>(Ah_ + r1_ + sw0); \
  bf16x8 a11 = *reinterpret_cast<const bf16x8*>(Ah_ + r1_ + sw1); \
  PIPE_MID_BAR(); \
  __builtin_amdgcn_s_setprio(1); \
  _Pragma("unroll") \
  for (int n_ = 0; n_ < 4; ++n_) { \
    acc[(F0)][n_]     = __builtin_amdgcn_mfma_f32_16x16x32_bf16(a00, breg[n_][0], acc[(F0)][n_], 0, 0, 0); \
    acc[(F0)][n_]     = __builtin_amdgcn_mfma_f32_16x16x32_bf16(a01, breg[n_][1], acc[(F0)][n_], 0, 0, 0); \
    acc[(F0) + 1][n_] = __builtin_amdgcn_mfma_f32_16x16x32_bf16(a10, breg[n_][0], acc[(F0) + 1][n_], 0, 0, 0); \
    acc[(F0) + 1][n_] = __builtin_amdgcn_mfma_f32_16x16x32_bf16(a11, breg[n_][1], acc[(F0) + 1][n_], 0, 0, 0); \
  } \
  __builtin_amdgcn_s_setprio(0); \
  PIPE_POST_BAR(); \
} while (0)

__global__ __launch_bounds__(512, 2) void gemm1_kernel(
    const unsigned short* __restrict__ xb,
    const unsigned short* __restrict__ w1t,   // [E][2048][512]
    const float* __restrict__ b1,
    const int* __restrict__ off,
    const int* __restrict__ list,
    unsigned short* __restrict__ H) {
  int e = blockIdx.x;                        // gridDim.x==8 -> linear%8==e -> XCD-pinned
  int offe = off[e];
  int cnt_e = off[e + 1] - offe;
  int n0 = blockIdx.y * 256;
  int m0 = blockIdx.z * 256;
  if (m0 >= cnt_e) return;

  __shared__ char ldsb[131072];

  int tid = threadIdx.x, wv = tid >> 6, lane = tid & 63;
  int wave_m = wv >> 2, wave_n = wv & 3;
  int lane16 = lane & 15, kq4 = lane >> 4;
  int ks = (lane & 7) ^ ((lane >> 3) & 7);
  int rl = lane >> 3;

  const unsigned short* w1e = w1t + (size_t)e * HIDN * DIMD;

  // staging sources (per-lane), h=half, i=instruction
  const unsigned short* aptr[2][2];
  const unsigned short* bptr[2][2];
#pragma unroll
  for (int h = 0; h < 2; ++h) {
#pragma unroll
    for (int i = 0; i < 2; ++i) {
      int r = (wv * 2 + i) * 8 + rl;         // row in half 0..127
      int grow = m0 + h * 128 + r;
      int tok = 0;
      if (grow < cnt_e) tok = list[offe + grow] >> 1;
      aptr[h][i] = xb + (size_t)tok * DIMD + ks * 8;
      bptr[h][i] = w1e + (size_t)(n0 + h * 128 + r) * DIMD + ks * 8;
    }
  }

  auto stA = [&](int kt2, int h) {
    char* base = ldsb + (kt2 & 1) * 32768 + h * 16384 + wv * 2048;
    gl16(aptr[h][0] + kt2 * 64, base);
    gl16(aptr[h][1] + kt2 * 64, base + 1024);
  };
  auto stB = [&](int kt2) {
    char* base = ldsb + 65536 + (kt2 & 1) * 32768 + wv * 2048;
    gl16(bptr[0][0] + kt2 * 64, base);
    gl16(bptr[0][1] + kt2 * 64, base + 1024);
    gl16(bptr[1][0] + kt2 * 64, base + 16384);
    gl16(bptr[1][1] + kt2 * 64, base + 16384 + 1024);
  };

  int sw0 = ((0 + kq4) ^ (lane16 & 7)) << 4;   // kk=0 chunk
  int sw1 = ((4 + kq4) ^ (lane16 & 7)) << 4;   // kk=1 chunk

  f32x4 zero = {0.f, 0.f, 0.f, 0.f};
  f32x4 acc[8][4];
#pragma unroll
  for (int m = 0; m < 8; ++m)
#pragma unroll
    for (int n = 0; n < 4; ++n) acc[m][n] = zero;

  // prologue: stage K-tiles 0 and 1 (8 gl16 each per wave)
  stB(0); stA(0, 0); stA(0, 1);
  stB(1); stA(1, 0); stA(1, 1);

  const int NT = DIMD / 64;   // 8 K-tiles
  for (int kt = 0; kt < NT; ++kt) {
    const char* A = ldsb + (kt & 1) * 32768;
    const char* B = ldsb + 65536 + (kt & 1) * 32768;
    if (kt < NT - 1) PIPE_WAIT8_BAR(); else PIPE_WAIT0_BAR();

    // B-frag register cache (8 ds_read_b128), part of phase 0
    bf16x8 breg[4][2];
    {
      const char* Bh = B + (wave_n >> 1) * 16384;
      int rb = ((wave_n & 1) * 64 + lane16) * 128;
#pragma unroll
      for (int n = 0; n < 4; ++n) {
        breg[n][0] = *reinterpret_cast<const bf16x8*>(Bh + rb + n * 2048 + sw0);
        breg[n][1] = *reinterpret_cast<const bf16x8*>(Bh + rb + n * 2048 + sw1);
      }
    }
    G1_PHASE(0);
    if (kt < NT - 2) stB(kt + 2);
    G1_PHASE(2);
    if (kt < NT - 2) stA(kt + 2, 0);
    G1_PHASE(4);
    G1_PHASE(6);
    if (kt < NT - 2) stA(kt + 2, 1);
  }

  // epilogue: gelu -> bf16, two 128-row chunks staged in LDS [128][264], uint4 store
  unsigned short* Ct = (unsigned short*)ldsb;
  const float* b1e = b1 + e * HIDN;
  float bias[4];
#pragma unroll
  for (int n = 0; n < 4; ++n) bias[n] = b1e[n0 + wave_n * 64 + n * 16 + lane16];
#pragma unroll
  for (int h = 0; h < 2; ++h) {
#pragma unroll
    for (int fq = 0; fq < 4; ++fq) {
#pragma unroll
      for (int n = 0; n < 4; ++n) {
        int cl = wave_n * 64 + n * 16 + lane16;
#pragma unroll
        for (int q = 0; q < 4; ++q) {
          int rl2 = wave_m * 64 + fq * 16 + kq4 * 4 + q;
          float v = acc[h * 4 + fq][n][q] + bias[n];
          float g = 0.5f * v * (1.f + erff(v * 0.70710678118654752f));
          Ct[rl2 * 264 + cl] = f2bf(g);
        }
      }
    }
    __syncthreads();
#pragma unroll
    for (int j = 0; j < 8; ++j) {
      int u = tid + j * 512;
      int row = u >> 5, c8 = (u & 31) * 8;
      int grow = m0 + h * 128 + row;
      if (grow < cnt_e) {
        uint4 v = *reinterpret_cast<const uint4*>(Ct + row * 264 + c8);
        *reinterpret_cast<uint4*>(H + (size_t)(offe + grow) * HIDN + n0 + c8) = v;
      }
    }
    __syncthreads();
  }
}

// ---------- GEMM2: Yw[a] = tw[a]*(H @ W2 + b2); counted-vmcnt dbuf BK=32 (round-8 proven) ----------
__global__ __launch_bounds__(256) void gemm2_kernel(
    const unsigned short* __restrict__ H,
    const unsigned short* __restrict__ w2t,   // [E][512][2048]
    const float* __restrict__ b2,
    const int* __restrict__ off,
    const int* __restrict__ list,
    const float* __restrict__ tw,
    float* __restrict__ Yw) {
  int e = blockIdx.x;
  int offe = off[e];
  int cnt_e = off[e + 1] - offe;
  int n0 = blockIdx.y * 128;
  int m0 = blockIdx.z * 128;
  if (m0 >= cnt_e) return;

  __shared__ char ldsb[32768];

  int tid = threadIdx.x, wv = tid >> 6, lane = tid & 63;
  int rp = lane >> 3, sl = lane & 7;
  int sx = sl ^ rp;
  int rowadd = rp * 2 + (sx >> 2);
  int kq = sx & 3;

  const unsigned short* w2e = w2t + (size_t)e * DIMD * HIDN;
  const unsigned short* asrc[2];
  const unsigned short* bsrc[2];
#pragma unroll
  for (int i = 0; i < 2; ++i) {
    int r = wv * 32 + i * 16 + rowadd;
    int rowa = offe + m0 + r;
    if (rowa > NASG - 1) rowa = NASG - 1;    // pad rows: clamp (values discarded)
    asrc[i] = H + (size_t)rowa * HIDN + kq * 8;
    bsrc[i] = w2e + (size_t)(n0 + r) * HIDN + kq * 8;
  }
  int dstA0 = wv * 2048;
  int dstA1 = wv * 2048 + 1024;

  f32x4 zero = {0.f, 0.f, 0.f, 0.f};
  f32x4 acc[4][4];
#pragma unroll
  for (int m = 0; m < 4; ++m)
#pragma unroll
    for (int n = 0; n < 4; ++n) acc[m][n] = zero;

  int wave_m = wv >> 1, wave_n = wv & 1;
  int lane16 = lane & 15, kq4 = lane >> 4;
  int ra[4], rb[4];
#pragma unroll
  for (int m = 0; m < 4; ++m) {
    int r = wave_m * 64 + m * 16 + lane16;
    ra[m] = (r >> 1) * 128 + ((((kq4 + (r & 1) * 4)) ^ ((r >> 1) & 7)) << 4);
    int rn = wave_n * 64 + m * 16 + lane16;
    rb[m] = (rn >> 1) * 128 + ((((kq4 + (rn & 1) * 4)) ^ ((rn >> 1) & 7)) << 4);
  }

  auto stage = [&](char* nb, int k0) {
    gl16(asrc[0] + k0, nb + dstA0);
    gl16(asrc[1] + k0, nb + dstA1);
    gl16(bsrc[0] + k0, nb + 8192 + dstA0);
    gl16(bsrc[1] + k0, nb + 8192 + dstA1);
  };
  auto compute = [&](const char* cb) {
    bf16x8 af[4], bfr[4];
#pragma unroll
    for (int m = 0; m < 4; ++m) af[m] = *reinterpret_cast<const bf16x8*>(cb + ra[m]);
#pragma unroll
    for (int n = 0; n < 4; ++n) bfr[n] = *reinterpret_cast<const bf16x8*>(cb + 8192 + rb[n]);
#pragma unroll
    for (int m = 0; m < 4; ++m)
#pragma unroll
      for (int n = 0; n < 4; ++n)
        acc[m][n] = __builtin_amdgcn_mfma_f32_16x16x32_bf16(af[m], bfr[n], acc[m][n], 0, 0, 0);
  };

  const int T = HIDN / 32;   // 64 steps
  stage(ldsb, 0);
  stage(ldsb + 16384, 32);
  for (int t = 0; t < T - 2; ++t) {
    char* cb = ldsb + (t & 1) * 16384;
    PIPE_WAIT4_BAR();
    compute(cb);
    PIPE_POST_BAR();
    stage(cb, (t + 2) * 32);
  }
  PIPE_WAIT4_BAR();
  compute(ldsb + ((T - 2) & 1) * 16384);
  PIPE_POST_BAR();
  PIPE_WAIT0_BAR();
  compute(ldsb + ((T - 1) & 1) * 16384);
  PIPE_POST_BAR();

  const float* b2e = b2 + e * DIMD;
  float bias[4];
#pragma unroll
  for (int n = 0; n < 4; ++n) bias[n] = b2e[n0 + wave_n * 64 + n * 16 + lane16];
#pragma unroll
  for (int m = 0; m < 4; ++m) {
#pragma unroll
    for (int q = 0; q < 4; ++q) {
      int r = m0 + wave_m * 64 + m * 16 + kq4 * 4 + q;
      if (r < cnt_e) {
        int a = list[offe + r];
        float w = tw[a];
        float* yrow = Yw + (size_t)a * DIMD;
#pragma unroll
        for (int n = 0; n < 4; ++n) {
          int col = n0 + wave_n * 64 + n * 16 + lane16;
          yrow[col] = w * (acc[m][n][q] + bias[n]);
        }
      }
    }
  }
}

// ---------- combine: out[n] = Yw[2n] + Yw[2n+1] ----------
__global__ __launch_bounds__(256) void combine_kernel(const float* __restrict__ Yw,
                                                      float* __restrict__ out) {
  int i = (blockIdx.x * 256 + threadIdx.x) * 4;
  int n = i >> 9;
  int d = i & 511;
  float4 a = *reinterpret_cast<const float4*>(Yw + (size_t)(2 * n) * DIMD + d);
  float4 b = *reinterpret_cast<const float4*>(Yw + (size_t)(2 * n + 1) * DIMD + d);
  float4 o;
  o.x = a.x + b.x; o.y = a.y + b.y; o.z = a.z + b.z; o.w = a.w + b.w;
  *reinterpret_cast<float4*>(out + i) = o;
}

extern "C" void kernel_launch(void* const* d_in, const int* in_sizes, int n_in,
                              void* d_out, int out_size, void* d_ws, size_t ws_size,
                              hipStream_t stream) {
  const float* x  = (const float*)d_in[0];
  const float* Wr = (const float*)d_in[1];
  const float* br = (const float*)d_in[2];
  const float* W1 = (const float*)d_in[3];
  const float* b1 = (const float*)d_in[4];
  const float* W2 = (const float*)d_in[5];
  const float* b2 = (const float*)d_in[6];
  float* out = (float*)d_out;

  char* ws = (char*)d_ws;
  unsigned short* xb  = (unsigned short*)ws;  ws += (size_t)NTOK * DIMD * 2;
  unsigned short* w1t = (unsigned short*)ws;  ws += (size_t)NEXP * HIDN * DIMD * 2;
  unsigned short* w2t = (unsigned short*)ws;  ws += (size_t)NEXP * DIMD * HIDN * 2;
  unsigned short* H   = (unsigned short*)ws;  ws += (size_t)NASG * HIDN * 2;
  float* Yw = (float*)ws;                     ws += (size_t)NASG * DIMD * 4;
  float* tw = (float*)ws;                     ws += (size_t)NASG * 4;
  int* tidx = (int*)ws;                       ws += (size_t)NASG * 4;
  int* list = (int*)ws;                       ws += (size_t)NASG * 4;
  int* offp = (int*)ws;                       // off[9]

  transpose_both_kernel<<<dim3(32, 8, 16), 256, 0, stream>>>(W1, W2, w1t, w2t);
  router_kernel<<<NTOK / 4, 256, 0, stream>>>(x, Wr, br, tidx, tw, xb);
  route_pack_kernel<<<1, 1024, 0, stream>>>(tidx, offp, list, out + (size_t)NTOK * DIMD);
  // expert = blockIdx.x -> grid-linear %8 == expert -> XCD-pinned weight panels
  gemm1_kernel<<<dim3(NEXP, HIDN / 256, NASG / 256), 512, 0, stream>>>(xb, w1t, b1, offp, list, H);
  gemm2_kernel<<<dim3(NEXP, DIMD / 128, NASG / 128), 256, 0, stream>>>(H, w2t, b2, offp, list, tw, Yw);
  combine_kernel<<<2048, 256, 0, stream>>>(Yw, out);
}